// Round 1
// baseline (2034.704 us; speedup 1.0000x reference)
//
#include <hip/hip_runtime.h>

#define CH 512
#define MIDC 512
#define TT 8192
#define WN 512
#define PP 16
#define OCH 1536
#define NEGC -1000000000.0f

// ---------------- Kernel A: QKV grouped conv (dilated along T) ----------------
// qkv[b,o,t] = b[o] + sum_{ci<64,kh<5} x[b, g*64+ci, t+(kh-2)*16] * W[o,ci,kh]
__global__ __launch_bounds__(256) void qkv_conv(
    const float* __restrict__ x, const float* __restrict__ Wq,
    const float* __restrict__ bq,
    float* __restrict__ qb, float* __restrict__ kb, float* __restrict__ vb)
{
    int tid = threadIdx.x;
    int t = blockIdx.x * 256 + tid;
    int ob = blockIdx.y * 8;
    int b = blockIdx.z;
    int g = ob / 192;
    int cbase = g * 64;

    __shared__ float wls[320 * 8];   // [(ci*5+kh)*8 + j]
    for (int idx = tid; idx < 320 * 8; idx += 256) {
        int j = idx & 7, m = idx >> 3;            // m = ci*5+kh
        wls[idx] = Wq[(size_t)(ob + j) * 320 + m];
    }
    __syncthreads();

    float acc[8];
#pragma unroll
    for (int j = 0; j < 8; j++) acc[j] = 0.f;

    const float* xb = x + ((size_t)(b * CH + cbase)) * TT;
#pragma unroll
    for (int kh = 0; kh < 5; kh++) {
        int tt = t + (kh - 2) * 16;
        if ((unsigned)tt < (unsigned)TT) {
            const float* xp = xb + tt;
#pragma unroll 4
            for (int ci = 0; ci < 64; ci++) {
                float xv = xp[(size_t)ci * TT];
                const float* wp = &wls[(ci * 5 + kh) * 8];
                float4 w0 = *(const float4*)(wp);
                float4 w1 = *(const float4*)(wp + 4);
                acc[0] += xv * w0.x; acc[1] += xv * w0.y;
                acc[2] += xv * w0.z; acc[3] += xv * w0.w;
                acc[4] += xv * w1.x; acc[5] += xv * w1.y;
                acc[6] += xv * w1.z; acc[7] += xv * w1.w;
            }
        }
    }

    int which = ob >> 9;                 // 0:q 1:k 2:v
    int oo = ob & 511;
    float* dst = (which == 0 ? qb : (which == 1 ? kb : vb))
               + ((size_t)(b * MIDC + oo)) * TT + t;
#pragma unroll
    for (int j = 0; j < 8; j++)
        dst[(size_t)j * TT] = acc[j] + bq[ob + j];
}

// ---------------- Kernel B: softmax over d=8192 for q, per (b,w) ----------------
__global__ __launch_bounds__(256) void softmax_q(float* __restrict__ qb)
{
    int w = blockIdx.x, b = blockIdx.y, tid = threadIdx.x;
    float* base = qb + (size_t)b * MIDC * TT + (size_t)w * 16;

    float val[32];
    float mx = -1e30f;
#pragma unroll
    for (int kk = 0; kk < 32; kk++) {
        int e = tid + kk * 256;
        float v = base[((size_t)(e >> 4)) * TT + (e & 15)];
        val[kk] = v;
        mx = fmaxf(mx, v);
    }
#pragma unroll
    for (int o = 32; o > 0; o >>= 1) mx = fmaxf(mx, __shfl_xor(mx, o));
    __shared__ float red[4];
    int wv = tid >> 6;
    if ((tid & 63) == 0) red[wv] = mx;
    __syncthreads();
    mx = fmaxf(fmaxf(red[0], red[1]), fmaxf(red[2], red[3]));

    float s = 0.f;
#pragma unroll
    for (int kk = 0; kk < 32; kk++) { val[kk] = __expf(val[kk] - mx); s += val[kk]; }
#pragma unroll
    for (int o = 32; o > 0; o >>= 1) s += __shfl_xor(s, o);
    __syncthreads();
    if ((tid & 63) == 0) red[wv] = s;
    __syncthreads();
    s = red[0] + red[1] + red[2] + red[3];
    float inv = 1.f / s;
#pragma unroll
    for (int kk = 0; kk < 32; kk++) {
        int e = tid + kk * 256;
        base[((size_t)(e >> 4)) * TT + (e & 15)] = val[kk] * inv;
    }
}

// ---------------- Kernel C: softmax over w=512 for k (+ drop mask), per (b,c) ----------------
__global__ __launch_bounds__(256) void softmax_k(
    float* __restrict__ kb, const float* __restrict__ mask)
{
    int c = blockIdx.x, b = blockIdx.y, tid = threadIdx.x;
    size_t off = ((size_t)(b * MIDC + c)) * TT;
    float* kp = kb + off;
    const float* mp = mask + off;   // drop_mask has identical (b,c,w,p) layout

    float val[32];
    float mx = -1e30f;
#pragma unroll
    for (int kk = 0; kk < 32; kk++) {
        int e = tid + kk * 256;       // p = e&15 = tid&15 (const per thread)
        float v = kp[e] + mp[e] * NEGC;
        val[kk] = v;
        mx = fmaxf(mx, v);
    }
    // reduce across threads sharing p = tid&15
    mx = fmaxf(mx, __shfl_xor(mx, 16));
    mx = fmaxf(mx, __shfl_xor(mx, 32));
    __shared__ float red[4][16];
    int wv = tid >> 6, ln = tid & 63;
    if (ln < 16) red[wv][ln] = mx;
    __syncthreads();
    int p = tid & 15;
    mx = fmaxf(fmaxf(red[0][p], red[1][p]), fmaxf(red[2][p], red[3][p]));

    float s = 0.f;
#pragma unroll
    for (int kk = 0; kk < 32; kk++) { val[kk] = __expf(val[kk] - mx); s += val[kk]; }
    s += __shfl_xor(s, 16);
    s += __shfl_xor(s, 32);
    __syncthreads();
    if (ln < 16) red[wv][ln] = s;
    __syncthreads();
    s = red[0][p] + red[1][p] + red[2][p] + red[3][p];
    float inv = 1.f / s;
#pragma unroll
    for (int kk = 0; kk < 32; kk++)
        kp[tid + kk * 256] = val[kk] * inv;
}

// ---------------- Kernel D: S[b,iw,w] = sum_{c,p} q[b,c,iw*16+p] k[b,c,w*16+p] ----------------
__global__ __launch_bounds__(256) void qk_gemm(
    const float* __restrict__ qb, const float* __restrict__ kb,
    float* __restrict__ S)
{
    int b = blockIdx.z;
    int iw0 = blockIdx.x * 32;
    int w0 = blockIdx.y * 32;
    int tid = threadIdx.x;
    int iw2 = tid >> 4;     // 0..15
    int w2 = tid & 15;      // 0..15

    __shared__ float qs[4 * 512];
    __shared__ float ks2[4 * 16 * 34];   // [cc][p][w] padded stride 34

    float acc00 = 0.f, acc01 = 0.f, acc10 = 0.f, acc11 = 0.f;
    const float* qbase = qb + (size_t)b * MIDC * TT + (size_t)iw0 * 16;
    const float* kbase = kb + (size_t)b * MIDC * TT + (size_t)w0 * 16;

    for (int c0 = 0; c0 < 512; c0 += 4) {
        __syncthreads();
#pragma unroll
        for (int l = 0; l < 8; l++) {
            int idx = tid + l * 256;      // 0..2047
            int cc = idx >> 9, i = idx & 511;
            float qv = qbase[(size_t)(c0 + cc) * TT + i];
            float kv = kbase[(size_t)(c0 + cc) * TT + i];
            qs[idx] = qv;
            int wl = i >> 4, pz = i & 15;
            ks2[(cc * 16 + pz) * 34 + wl] = kv;
        }
        __syncthreads();
#pragma unroll
        for (int cc = 0; cc < 4; cc++) {
            float qa0[16], qa1[16];
#pragma unroll
            for (int q4 = 0; q4 < 4; q4++) {
                float4 v0 = *(const float4*)&qs[cc * 512 + (iw2 * 2 + 0) * 16 + q4 * 4];
                float4 v1 = *(const float4*)&qs[cc * 512 + (iw2 * 2 + 1) * 16 + q4 * 4];
                qa0[q4 * 4 + 0] = v0.x; qa0[q4 * 4 + 1] = v0.y;
                qa0[q4 * 4 + 2] = v0.z; qa0[q4 * 4 + 3] = v0.w;
                qa1[q4 * 4 + 0] = v1.x; qa1[q4 * 4 + 1] = v1.y;
                qa1[q4 * 4 + 2] = v1.z; qa1[q4 * 4 + 3] = v1.w;
            }
#pragma unroll
            for (int pz = 0; pz < 16; pz++) {
                float2 kv = *(const float2*)&ks2[(cc * 16 + pz) * 34 + w2 * 2];
                acc00 += qa0[pz] * kv.x; acc01 += qa0[pz] * kv.y;
                acc10 += qa1[pz] * kv.x; acc11 += qa1[pz] * kv.y;
            }
        }
    }
    size_t r0 = ((size_t)b * WN + iw0 + iw2 * 2) * WN + w0 + w2 * 2;
    S[r0] = acc00;      S[r0 + 1] = acc01;
    S[r0 + WN] = acc10; S[r0 + WN + 1] = acc11;
}

// ---------------- Kernel E: attn[b,c,iw*16+p] = sum_w S[b,iw,w] v[b,c,w*16+p] ----------------
__global__ __launch_bounds__(256) void sv_gemm(
    const float* __restrict__ S, const float* __restrict__ vbuf,
    float* __restrict__ abuf)
{
    int b = blockIdx.z;
    int c = blockIdx.y;
    int iw0 = blockIdx.x * 128;
    int tid = threadIdx.x;
    int p = tid & 15, il = tid >> 4;

    __shared__ float Sls[128 * 33];
    __shared__ float Vls[512];
    float acc[8];
#pragma unroll
    for (int j = 0; j < 8; j++) acc[j] = 0.f;

    const float* Sb = S + (size_t)b * WN * WN;
    const float* vb = vbuf + ((size_t)(b * MIDC + c)) * TT;

    for (int wc = 0; wc < 512; wc += 32) {
        __syncthreads();
#pragma unroll
        for (int l = 0; l < 16; l++) {
            int idx = tid + l * 256;     // 0..4095
            int r = idx >> 5, wl = idx & 31;
            Sls[r * 33 + wl] = Sb[(size_t)(iw0 + r) * WN + wc + wl];
        }
#pragma unroll
        for (int l = 0; l < 2; l++) {
            int idx = tid + l * 256;
            Vls[idx] = vb[(size_t)wc * 16 + idx];
        }
        __syncthreads();
#pragma unroll
        for (int w = 0; w < 32; w++) {
            float vv = Vls[w * 16 + p];
#pragma unroll
            for (int j = 0; j < 8; j++)
                acc[j] += Sls[(il + j * 16) * 33 + w] * vv;
        }
    }
#pragma unroll
    for (int j = 0; j < 8; j++)
        abuf[((size_t)(b * MIDC + c)) * TT + (size_t)(iw0 + il + j * 16) * 16 + p] = acc[j];
}

// ---------------- Kernel F: out conv1d (512ci x 3, pad 1) ----------------
__global__ __launch_bounds__(256) void out_conv(
    const float* __restrict__ abuf, const float* __restrict__ Wo,
    const float* __restrict__ bo, float* __restrict__ out)
{
    int tid = threadIdx.x;
    int t = blockIdx.x * 256 + tid;
    int co_b = blockIdx.y * 8;
    int b = blockIdx.z;

    __shared__ float wls[512 * 3 * 8];   // [(ci*3+kt)*8 + j]
    for (int idx = tid; idx < 512 * 3 * 8; idx += 256) {
        int j = idx & 7, m = idx >> 3;
        wls[idx] = Wo[(size_t)(co_b + j) * 1536 + m];
    }
    __syncthreads();

    float acc[8];
#pragma unroll
    for (int j = 0; j < 8; j++) acc[j] = 0.f;

    const float* ap = abuf + (size_t)b * MIDC * TT + t;
    for (int ci = 0; ci < 512; ci++) {
        const float* row = ap + (size_t)ci * TT;
        float xm = (t > 0) ? row[-1] : 0.f;
        float x0 = row[0];
        float xp = (t < TT - 1) ? row[1] : 0.f;
        const float* wp = &wls[ci * 24];
        float4 a0 = *(const float4*)(wp + 0),  a1 = *(const float4*)(wp + 4);
        float4 b0 = *(const float4*)(wp + 8),  b1 = *(const float4*)(wp + 12);
        float4 c0 = *(const float4*)(wp + 16), c1 = *(const float4*)(wp + 20);
        acc[0] += xm * a0.x + x0 * b0.x + xp * c0.x;
        acc[1] += xm * a0.y + x0 * b0.y + xp * c0.y;
        acc[2] += xm * a0.z + x0 * b0.z + xp * c0.z;
        acc[3] += xm * a0.w + x0 * b0.w + xp * c0.w;
        acc[4] += xm * a1.x + x0 * b1.x + xp * c1.x;
        acc[5] += xm * a1.y + x0 * b1.y + xp * c1.y;
        acc[6] += xm * a1.z + x0 * b1.z + xp * c1.z;
        acc[7] += xm * a1.w + x0 * b1.w + xp * c1.w;
    }
#pragma unroll
    for (int j = 0; j < 8; j++)
        out[((size_t)(b * CH + co_b + j)) * TT + t] = acc[j] + bo[co_b + j];
}

extern "C" void kernel_launch(void* const* d_in, const int* in_sizes, int n_in,
                              void* d_out, int out_size, void* d_ws, size_t ws_size,
                              hipStream_t stream)
{
    const float* x    = (const float*)d_in[0];   // (2,512,8192)
    const float* Wq   = (const float*)d_in[1];   // (1536,64,5,1)
    const float* bq   = (const float*)d_in[2];   // (1536,)
    const float* Wo   = (const float*)d_in[3];   // (512,512,3)
    const float* bo   = (const float*)d_in[4];   // (512,)
    const float* mask = (const float*)d_in[5];   // (2,512,512,16)
    float* out = (float*)d_out;                  // (2,512,8192)

    float* ws = (float*)d_ws;
    const size_t N1 = (size_t)2 * MIDC * TT;     // 8388608 per tensor
    float* qb = ws;
    float* kb = qb + N1;
    float* vb = kb + N1;
    float* sb = vb + N1;                         // 2*512*512
    float* ab = sb + (size_t)2 * WN * WN;

    qkv_conv<<<dim3(TT / 256, OCH / 8, 2), 256, 0, stream>>>(x, Wq, bq, qb, kb, vb);
    softmax_q<<<dim3(WN, 2), 256, 0, stream>>>(qb);
    softmax_k<<<dim3(MIDC, 2), 256, 0, stream>>>(kb, mask);
    qk_gemm<<<dim3(WN / 32, WN / 32, 2), 256, 0, stream>>>(qb, kb, sb);
    sv_gemm<<<dim3(WN / 128, MIDC, 2), 256, 0, stream>>>(sb, vb, ab);
    out_conv<<<dim3(TT / 256, CH / 8, 2), 256, 0, stream>>>(ab, Wo, bo, out);
}

// Round 2
// 345.461 us; speedup vs baseline: 5.8898x; 5.8898x over previous
//
#include <hip/hip_runtime.h>

#define CH 512
#define TT 8192
#define WN 512
#define NEGC -1000000000.0f

typedef _Float16 f16;
typedef f16 half8 __attribute__((ext_vector_type(8)));
typedef float floatx16 __attribute__((ext_vector_type(16)));

#define MFMA(a, b, c) __builtin_amdgcn_mfma_f32_32x32x16_f16(a, b, c, 0, 0, 0)

// LDS operand tiles: [row][64 k] f16, row stride 128B, 16B chunks XOR-swizzled by (row&7).
__device__ __forceinline__ half8 lds_read_frag(const f16* lds, int row, int chunk) {
    return *(const half8*)(lds + row * 64 + (((chunk ^ (row & 7))) << 3));
}
__device__ __forceinline__ void lds_write_chunk(f16* lds, int row, int chunk, half8 v) {
    *(half8*)(lds + row * 64 + ((chunk ^ (row & 7)) << 3)) = v;
}

// ---------------- prep: weights -> tap-decomposed fp16 ----------------
// Wq5[kh][o][ci]  (5 x 1536 x 64),  Wo3[kt][co][ci] (3 x 512 x 512)
__global__ __launch_bounds__(256) void prep_w(
    const float* __restrict__ Wq, const float* __restrict__ Wo,
    f16* __restrict__ Wq5, f16* __restrict__ Wo3)
{
    int i = blockIdx.x * 256 + threadIdx.x;
    const int NQ = 5 * 1536 * 64;
    if (i < NQ) {
        int kh = i / (1536 * 64);
        int r = i % (1536 * 64);
        int o = r >> 6, ci = r & 63;
        Wq5[i] = (f16)Wq[o * 320 + ci * 5 + kh];
    } else {
        int j = i - NQ;
        if (j < 3 * 512 * 512) {
            int kt = j / (512 * 512);
            int r = j % (512 * 512);
            int co = r >> 9, ci = r & 511;
            Wo3[j] = (f16)Wo[co * 1536 + ci * 3 + kt];
        }
    }
}

// ---------------- transpose+cvt: src[b][512 c][8192 t] f32 -> dst[b][8192 t][512 c] f16 ----------------
__global__ __launch_bounds__(256) void transpose_cvt(
    const float* __restrict__ src, size_t bstride, f16* __restrict__ dst)
{
    __shared__ float tl[64][65];
    int tid = threadIdx.x;
    int t0 = blockIdx.x * 64, c0 = blockIdx.y * 64, b = blockIdx.z;
    const float* sp = src + (size_t)b * bstride + (size_t)c0 * TT + t0;
#pragma unroll
    for (int i = 0; i < 16; i++) {
        int row = (tid >> 6) + i * 4;
        tl[row][tid & 63] = sp[(size_t)row * TT + (tid & 63)];
    }
    __syncthreads();
    f16* dp = dst + ((size_t)b * TT + t0) * 512 + c0;
#pragma unroll
    for (int i = 0; i < 16; i++) {
        int t = (tid >> 6) + i * 4;
        dp[(size_t)t * 512 + (tid & 63)] = (f16)tl[tid & 63][t];
    }
}

// ---------------- QKV grouped conv as 5-tap MFMA GEMM ----------------
// D[o][t] = sum_kh sum_ci Wq5[kh][o][ci] * xT[t+(kh-2)*16][g*64+ci]
__global__ __launch_bounds__(256) void qkv_mfma(
    const f16* __restrict__ xT, const f16* __restrict__ Wq5, const float* __restrict__ bq,
    float* __restrict__ qkb, f16* __restrict__ vb16)
{
    __shared__ f16 xs[320 * 64];   // rows t0-32 .. t0+288, 64 ci
    int tid = threadIdx.x;
    int b = blockIdx.x >> 5;
    int t0 = (blockIdx.x & 31) * 256;
    int m = blockIdx.y;            // 0..23
    int ob = m * 64;
    int g = m / 3;

    const f16* xb = xT + ((size_t)b * TT) * 512 + g * 64;
#pragma unroll
    for (int l = 0; l < 10; l++) {
        int q = tid + l * 256;          // < 2560
        int row = q >> 3, c16 = q & 7;
        int t = t0 - 32 + row;
        half8 v = {};
        if ((unsigned)t < (unsigned)TT) v = *(const half8*)(xb + (size_t)t * 512 + c16 * 8);
        lds_write_chunk(xs, row, c16, v);
    }
    __syncthreads();

    int wid = tid >> 6, l = tid & 63;
    int ln31 = l & 31, lhi = l >> 5;
    floatx16 acc[2][2] = {};
#pragma unroll
    for (int kh = 0; kh < 5; kh++) {
        const f16* wk = Wq5 + (size_t)kh * 1536 * 64;
#pragma unroll
        for (int ks = 0; ks < 4; ks++) {
            half8 a0 = *(const half8*)(wk + (size_t)(ob + ln31) * 64 + ks * 16 + lhi * 8);
            half8 a1 = *(const half8*)(wk + (size_t)(ob + 32 + ln31) * 64 + ks * 16 + lhi * 8);
            int chunk = ks * 2 + lhi;
            int r0 = wid * 64 + kh * 16 + ln31;
            half8 b0 = lds_read_frag(xs, r0, chunk);
            half8 b1 = lds_read_frag(xs, r0 + 32, chunk);
            acc[0][0] = MFMA(a0, b0, acc[0][0]);
            acc[0][1] = MFMA(a0, b1, acc[0][1]);
            acc[1][0] = MFMA(a1, b0, acc[1][0]);
            acc[1][1] = MFMA(a1, b1, acc[1][1]);
        }
    }
#pragma unroll
    for (int mf = 0; mf < 2; mf++)
#pragma unroll
        for (int nf = 0; nf < 2; nf++)
#pragma unroll
            for (int r = 0; r < 16; r++) {
                int o = ob + mf * 32 + (r & 3) + 8 * (r >> 2) + 4 * lhi;
                int t = t0 + wid * 64 + nf * 32 + ln31;
                float val = acc[mf][nf][r] + bq[o];
                if (o < 1024)
                    qkb[((size_t)b * 1024 + o) * TT + t] = val;
                else
                    vb16[((size_t)b * 512 + (o - 1024)) * TT + t] = (f16)val;
            }
}

// ---------------- softmax over d=8192 for q, per (b,w)  [f32 in-place] ----------------
__global__ __launch_bounds__(256) void softmax_q(float* __restrict__ qkb)
{
    int w = blockIdx.x, b = blockIdx.y, tid = threadIdx.x;
    float* base = qkb + (size_t)b * 1024 * TT + (size_t)w * 16;

    float val[32];
    float mx = -1e30f;
#pragma unroll
    for (int kk = 0; kk < 32; kk++) {
        int e = tid + kk * 256;
        float v = base[((size_t)(e >> 4)) * TT + (e & 15)];
        val[kk] = v;
        mx = fmaxf(mx, v);
    }
#pragma unroll
    for (int o = 32; o > 0; o >>= 1) mx = fmaxf(mx, __shfl_xor(mx, o));
    __shared__ float red[4];
    int wv = tid >> 6;
    if ((tid & 63) == 0) red[wv] = mx;
    __syncthreads();
    mx = fmaxf(fmaxf(red[0], red[1]), fmaxf(red[2], red[3]));

    float s = 0.f;
#pragma unroll
    for (int kk = 0; kk < 32; kk++) { val[kk] = __expf(val[kk] - mx); s += val[kk]; }
#pragma unroll
    for (int o = 32; o > 0; o >>= 1) s += __shfl_xor(s, o);
    __syncthreads();
    if ((tid & 63) == 0) red[wv] = s;
    __syncthreads();
    s = red[0] + red[1] + red[2] + red[3];
    float inv = 1.f / s;
#pragma unroll
    for (int kk = 0; kk < 32; kk++) {
        int e = tid + kk * 256;
        base[((size_t)(e >> 4)) * TT + (e & 15)] = val[kk] * inv;
    }
}

// ---------------- softmax over w=512 for k (+ drop mask), per (b,c) [f32 in-place] ----------------
__global__ __launch_bounds__(256) void softmax_k(
    float* __restrict__ qkb, const float* __restrict__ mask)
{
    int c = blockIdx.x, b = blockIdx.y, tid = threadIdx.x;
    float* kp = qkb + ((size_t)(b * 1024 + 512 + c)) * TT;
    const float* mp = mask + ((size_t)(b * 512 + c)) * TT;

    float val[32];
    float mx = -1e30f;
#pragma unroll
    for (int kk = 0; kk < 32; kk++) {
        int e = tid + kk * 256;
        float v = kp[e] + mp[e] * NEGC;
        val[kk] = v;
        mx = fmaxf(mx, v);
    }
    mx = fmaxf(mx, __shfl_xor(mx, 16));
    mx = fmaxf(mx, __shfl_xor(mx, 32));
    __shared__ float red[4][16];
    int wv = tid >> 6, ln = tid & 63;
    if (ln < 16) red[wv][ln] = mx;
    __syncthreads();
    int p = tid & 15;
    mx = fmaxf(fmaxf(red[0][p], red[1][p]), fmaxf(red[2][p], red[3][p]));

    float s = 0.f;
#pragma unroll
    for (int kk = 0; kk < 32; kk++) { val[kk] = __expf(val[kk] - mx); s += val[kk]; }
    s += __shfl_xor(s, 16);
    s += __shfl_xor(s, 32);
    __syncthreads();
    if (ln < 16) red[wv][ln] = s;
    __syncthreads();
    s = red[0][p] + red[1][p] + red[2][p] + red[3][p];
    float inv = 1.f / s;
#pragma unroll
    for (int kk = 0; kk < 32; kk++)
        kp[tid + kk * 256] = val[kk] * inv;
}

// ---------------- v permute: vb16[b][c][t] -> vpw[b][c][p][w]  (t = w*16+p) ----------------
__global__ __launch_bounds__(256) void vperm(
    const f16* __restrict__ vb16, f16* __restrict__ vpw)
{
    int c = blockIdx.x, b = blockIdx.y, tid = threadIdx.x;
    __shared__ f16 tl[512 * 17];
    const f16* ip = vb16 + ((size_t)b * 512 + c) * TT;
    f16* op = vpw + ((size_t)b * 512 + c) * 16 * 512;
#pragma unroll
    for (int i = 0; i < 32; i++) {
        int e = tid + i * 256;
        tl[(e >> 4) * 17 + (e & 15)] = ip[e];
    }
    __syncthreads();
#pragma unroll
    for (int i = 0; i < 32; i++) {
        int o = tid + i * 256;           // o = p*512 + w
        op[o] = tl[(o & 511) * 17 + (o >> 9)];
    }
}

__global__ __launch_bounds__(256) void zero_s(float* __restrict__ S)
{
    S[(size_t)blockIdx.x * 256 + threadIdx.x] = 0.f;
}

// ---------------- S[b][iw][w] += sum_k qT[iw*16+p][c] * kT[w*16+p][c], split-K ----------------
__global__ __launch_bounds__(256) void qk_mfma(
    const f16* __restrict__ qT, const f16* __restrict__ kT, float* __restrict__ S)
{
    __shared__ f16 As[128 * 64];
    __shared__ f16 Bs[128 * 64];
    int tid = threadIdx.x;
    int mt = blockIdx.x & 3, nt = blockIdx.x >> 2;
    int kz = blockIdx.y, b = blockIdx.z;
    int iw0 = mt * 128, w0 = nt * 128;
    const f16* qb_ = qT + (size_t)b * TT * 512;
    const f16* kb_ = kT + (size_t)b * TT * 512;
    int wid = tid >> 6, l = tid & 63, ln31 = l & 31, lhi = l >> 5;
    int wm = (wid >> 1) * 64, wn = (wid & 1) * 64;
    floatx16 acc[2][2] = {};

    for (int step = 0; step < 8; step++) {
        int k0 = kz * 512 + step * 64;
        int p0 = k0 >> 9, c0 = k0 & 511;
        __syncthreads();
#pragma unroll
        for (int li = 0; li < 4; li++) {
            int q = tid + li * 256;       // < 1024
            int row = q >> 3, c16 = q & 7;
            half8 av = *(const half8*)(qb_ + ((size_t)((iw0 + row) * 16 + p0)) * 512 + c0 + c16 * 8);
            half8 bv = *(const half8*)(kb_ + ((size_t)((w0 + row) * 16 + p0)) * 512 + c0 + c16 * 8);
            lds_write_chunk(As, row, c16, av);
            lds_write_chunk(Bs, row, c16, bv);
        }
        __syncthreads();
#pragma unroll
        for (int ks = 0; ks < 4; ks++) {
            int chunk = ks * 2 + lhi;
            half8 a0 = lds_read_frag(As, wm + ln31, chunk);
            half8 a1 = lds_read_frag(As, wm + 32 + ln31, chunk);
            half8 b0 = lds_read_frag(Bs, wn + ln31, chunk);
            half8 b1 = lds_read_frag(Bs, wn + 32 + ln31, chunk);
            acc[0][0] = MFMA(a0, b0, acc[0][0]);
            acc[0][1] = MFMA(a0, b1, acc[0][1]);
            acc[1][0] = MFMA(a1, b0, acc[1][0]);
            acc[1][1] = MFMA(a1, b1, acc[1][1]);
        }
    }
    float* Sb = S + (size_t)b * WN * WN;
#pragma unroll
    for (int mf = 0; mf < 2; mf++)
#pragma unroll
        for (int nf = 0; nf < 2; nf++)
#pragma unroll
            for (int r = 0; r < 16; r++) {
                int iw = iw0 + wm + mf * 32 + (r & 3) + 8 * (r >> 2) + 4 * lhi;
                int w = w0 + wn + nf * 32 + ln31;
                atomicAdd(&Sb[(size_t)iw * WN + w], acc[mf][nf][r]);
            }
}

// ---------------- abuf_T[b][iw*16+p][c] = sum_w S[b][iw][w] * vpw[b][c][p][w] ----------------
__global__ __launch_bounds__(256) void sv_mfma(
    const float* __restrict__ S, const f16* __restrict__ vpw, f16* __restrict__ abufT)
{
    __shared__ f16 As[128 * 64];
    __shared__ f16 Bs[128 * 64];
    int tid = threadIdx.x;
    int mt = blockIdx.x, nt = blockIdx.y;
    int b = blockIdx.z >> 4, p = blockIdx.z & 15;
    int iw0 = mt * 128, c0n = nt * 128;
    const float* Sb = S + (size_t)b * WN * WN;
    const f16* vb_ = vpw + ((size_t)b * 512) * 16 * 512;
    int wid = tid >> 6, l = tid & 63, ln31 = l & 31, lhi = l >> 5;
    int wm = (wid >> 1) * 64, wn = (wid & 1) * 64;
    floatx16 acc[2][2] = {};

    for (int step = 0; step < 8; step++) {
        int w0k = step * 64;
        __syncthreads();
#pragma unroll
        for (int li = 0; li < 4; li++) {
            int q = tid + li * 256;
            int row = q >> 3, c16 = q & 7;
            const float* sp = Sb + (size_t)(iw0 + row) * WN + w0k + c16 * 8;
            float4 f0 = *(const float4*)(sp);
            float4 f1 = *(const float4*)(sp + 4);
            half8 av;
            av[0] = (f16)f0.x; av[1] = (f16)f0.y; av[2] = (f16)f0.z; av[3] = (f16)f0.w;
            av[4] = (f16)f1.x; av[5] = (f16)f1.y; av[6] = (f16)f1.z; av[7] = (f16)f1.w;
            half8 bv = *(const half8*)(vb_ + ((size_t)(c0n + row) * 16 + p) * 512 + w0k + c16 * 8);
            lds_write_chunk(As, row, c16, av);
            lds_write_chunk(Bs, row, c16, bv);
        }
        __syncthreads();
#pragma unroll
        for (int ks = 0; ks < 4; ks++) {
            int chunk = ks * 2 + lhi;
            half8 a0 = lds_read_frag(As, wm + ln31, chunk);
            half8 a1 = lds_read_frag(As, wm + 32 + ln31, chunk);
            half8 b0 = lds_read_frag(Bs, wn + ln31, chunk);
            half8 b1 = lds_read_frag(Bs, wn + 32 + ln31, chunk);
            acc[0][0] = MFMA(a0, b0, acc[0][0]);
            acc[0][1] = MFMA(a0, b1, acc[0][1]);
            acc[1][0] = MFMA(a1, b0, acc[1][0]);
            acc[1][1] = MFMA(a1, b1, acc[1][1]);
        }
    }
#pragma unroll
    for (int mf = 0; mf < 2; mf++)
#pragma unroll
        for (int nf = 0; nf < 2; nf++)
#pragma unroll
            for (int r = 0; r < 16; r++) {
                int iw = iw0 + wm + mf * 32 + (r & 3) + 8 * (r >> 2) + 4 * lhi;
                int c = c0n + wn + nf * 32 + ln31;
                int t = iw * 16 + p;
                abufT[((size_t)b * TT + t) * 512 + c] = (f16)acc[mf][nf][r];
            }
}

// ---------------- out conv1d as 3-tap MFMA GEMM ----------------
// out[co][t] = sum_kt sum_ci Wo3[kt][co][ci] * abufT[t+kt-1][ci] + bo[co]
__global__ __launch_bounds__(256) void out_mfma(
    const f16* __restrict__ abufT, const f16* __restrict__ Wo3, const float* __restrict__ bo,
    float* __restrict__ out)
{
    __shared__ f16 Bs[130 * 64];
    int tid = threadIdx.x;
    int b = blockIdx.x >> 6;
    int t0 = (blockIdx.x & 63) * 128;
    int co0 = blockIdx.y * 128;
    const f16* ab = abufT + ((size_t)b * TT) * 512;
    int wid = tid >> 6, l = tid & 63, ln31 = l & 31, lhi = l >> 5;
    int wm = (wid >> 1) * 64, wn = (wid & 1) * 64;
    floatx16 acc[2][2] = {};

    for (int kc = 0; kc < 8; kc++) {
        int ci0 = kc * 64;
        __syncthreads();
#pragma unroll
        for (int li = 0; li < 5; li++) {
            int q = tid + li * 256;
            if (q < 1040) {
                int row = q >> 3, c16 = q & 7;
                int t = t0 - 1 + row;
                half8 v = {};
                if ((unsigned)t < (unsigned)TT) v = *(const half8*)(ab + (size_t)t * 512 + ci0 + c16 * 8);
                lds_write_chunk(Bs, row, c16, v);
            }
        }
        __syncthreads();
#pragma unroll
        for (int kt = 0; kt < 3; kt++) {
            const f16* wk = Wo3 + (size_t)kt * 512 * 512 + ci0;
#pragma unroll
            for (int ks = 0; ks < 4; ks++) {
                half8 a0 = *(const half8*)(wk + (size_t)(co0 + wm + ln31) * 512 + ks * 16 + lhi * 8);
                half8 a1 = *(const half8*)(wk + (size_t)(co0 + wm + 32 + ln31) * 512 + ks * 16 + lhi * 8);
                int chunk = ks * 2 + lhi;
                int r0 = wn + ln31 + kt;
                half8 b0 = lds_read_frag(Bs, r0, chunk);
                half8 b1 = lds_read_frag(Bs, r0 + 32, chunk);
                acc[0][0] = MFMA(a0, b0, acc[0][0]);
                acc[0][1] = MFMA(a0, b1, acc[0][1]);
                acc[1][0] = MFMA(a1, b0, acc[1][0]);
                acc[1][1] = MFMA(a1, b1, acc[1][1]);
            }
        }
    }
#pragma unroll
    for (int mf = 0; mf < 2; mf++)
#pragma unroll
        for (int nf = 0; nf < 2; nf++)
#pragma unroll
            for (int r = 0; r < 16; r++) {
                int co = co0 + wm + mf * 32 + (r & 3) + 8 * (r >> 2) + 4 * lhi;
                int t = t0 + wn + nf * 32 + ln31;
                out[((size_t)b * CH + co) * TT + t] = acc[mf][nf][r] + bo[co];
            }
}

extern "C" void kernel_launch(void* const* d_in, const int* in_sizes, int n_in,
                              void* d_out, int out_size, void* d_ws, size_t ws_size,
                              hipStream_t stream)
{
    const float* x    = (const float*)d_in[0];   // (2,512,8192)
    const float* Wq   = (const float*)d_in[1];   // (1536,64,5,1)
    const float* bq   = (const float*)d_in[2];   // (1536,)
    const float* Wo   = (const float*)d_in[3];   // (512,512,3)
    const float* bo   = (const float*)d_in[4];   // (512,)
    const float* mask = (const float*)d_in[5];   // (2,512,512,16)
    float* out = (float*)d_out;                  // (2,512,8192)
    (void)in_sizes; (void)n_in; (void)out_size; (void)ws_size;

    char* W = (char*)d_ws;
    // layout (total ~132.5 MiB):
    float* qkb  = (float*)W;                               // 2*1024*8192 f32 = 64 MiB (q:[0,512), k:[512,1024))
    f16*   vpw  = (f16*)W;                                 // alias (16 MiB) - written after q consumed
    f16*   xT   = (f16*)(W + 67108864);                    // 16 MiB  (aliased as abufT later)
    f16*   abufT = xT;
    f16*   vb16 = (f16*)(W + 67108864 + 16777216);         // 16 MiB
    f16*   qT   = (f16*)(W + 67108864 + 2 * 16777216);     // 16 MiB
    f16*   kT   = (f16*)(W + 67108864 + 3 * 16777216);     // 16 MiB
    float* S    = (float*)(W + 67108864 + 4 * 16777216);   // 2 MiB
    f16*   Wq5  = (f16*)(W + 67108864 + 4 * 16777216 + 2097152);
    f16*   Wo3  = (f16*)(W + 67108864 + 4 * 16777216 + 2097152 + 983040);

    prep_w<<<4992, 256, 0, stream>>>(Wq, Wo, Wq5, Wo3);
    transpose_cvt<<<dim3(128, 8, 2), 256, 0, stream>>>(x, (size_t)512 * TT, xT);
    qkv_mfma<<<dim3(64, 24), 256, 0, stream>>>(xT, Wq5, bq, qkb, vb16);
    softmax_q<<<dim3(WN, 2), 256, 0, stream>>>(qkb);
    softmax_k<<<dim3(512, 2), 256, 0, stream>>>(qkb, mask);
    transpose_cvt<<<dim3(128, 8, 2), 256, 0, stream>>>(qkb, (size_t)1024 * TT, qT);
    transpose_cvt<<<dim3(128, 8, 2), 256, 0, stream>>>(qkb + (size_t)512 * TT, (size_t)1024 * TT, kT);
    vperm<<<dim3(512, 2), 256, 0, stream>>>(vb16, vpw);
    zero_s<<<2048, 256, 0, stream>>>(S);
    qk_mfma<<<dim3(16, 16, 2), 256, 0, stream>>>(qT, kT, S);
    sv_mfma<<<dim3(4, 4, 32), 256, 0, stream>>>(S, vpw, abufT);
    out_mfma<<<dim3(128, 4), 256, 0, stream>>>(abufT, Wo3, bo, out);
}

// Round 6
// 286.880 us; speedup vs baseline: 7.0925x; 1.2042x over previous
//
#include <hip/hip_runtime.h>

#define TT 8192
#define NEGC -1000000000.0f

typedef _Float16 f16;
typedef f16 half8 __attribute__((ext_vector_type(8)));
typedef float floatx16 __attribute__((ext_vector_type(16)));

#define MFMA(a, b, c) __builtin_amdgcn_mfma_f32_32x32x16_f16(a, b, c, 0, 0, 0)

// LDS operand tiles: [row][64 k] f16, row stride 128B, 16B chunks XOR-swizzled by (row&7).
__device__ __forceinline__ half8 lds_read_frag(const f16* lds, int row, int chunk) {
    return *(const half8*)(lds + row * 64 + ((chunk ^ (row & 7)) << 3));
}
__device__ __forceinline__ void lds_write_chunk(f16* lds, int row, int chunk, half8 v) {
    *(half8*)(lds + row * 64 + ((chunk ^ (row & 7)) << 3)) = v;
}

// ---------------- prep: weights -> fragment-major packed fp16 ----------------
// WqP: frag idx (cb*5+kh)*4+ks, cb<48: lane l holds Wq[o=cb*32+(l&31)][ci=ks*16+(l>>5)*8+e][kh]
// WoP: frag idx ((cb*3+kt)*8+kc)*4+ks, cb<16: lane l holds Wo[co=cb*32+(l&31)][ci=kc*64+ks*16+(l>>5)*8+e][kt]
__global__ __launch_bounds__(256) void prep_w(
    const float* __restrict__ Wq, const float* __restrict__ Wo,
    f16* __restrict__ WqP, f16* __restrict__ WoP)
{
    int i = blockIdx.x * 256 + threadIdx.x;
    const int NQ = 48 * 5 * 4 * 512;        // 491520
    if (i < NQ) {
        int idx = i & 511, l = idx >> 3, e = idx & 7;
        int fi = i >> 9;
        int ks = fi & 3; fi >>= 2;
        int kh = fi % 5; int cb = fi / 5;
        int o = cb * 32 + (l & 31);
        int ci = ks * 16 + (l >> 5) * 8 + e;
        WqP[i] = (f16)Wq[o * 320 + ci * 5 + kh];
    } else {
        int j = i - NQ;
        if (j < 16 * 3 * 8 * 4 * 512) {     // 786432
            int idx = j & 511, l = idx >> 3, e = idx & 7;
            int fj = j >> 9;
            int ks = fj & 3; fj >>= 2;
            int kc = fj & 7; fj >>= 3;
            int kt = fj % 3; int cb = fj / 3;
            int co = cb * 32 + (l & 31);
            int ci = kc * 64 + ks * 16 + (l >> 5) * 8 + e;
            WoP[j] = (f16)Wo[co * 1536 + ci * 3 + kt];
        }
    }
}

// ---------------- transpose+cvt: src[b][512 c][8192 t] f32 -> dst[b][8192 t][512 c] f16 ----------------
__global__ __launch_bounds__(256) void transpose_cvt(
    const float* __restrict__ src, size_t bstride, f16* __restrict__ dst)
{
    __shared__ float tl[64][65];
    int tid = threadIdx.x;
    int t0 = blockIdx.x * 64, c0 = blockIdx.y * 64, b = blockIdx.z;
    const float* sp = src + (size_t)b * bstride + (size_t)c0 * TT + t0;
#pragma unroll
    for (int i = 0; i < 16; i++) {
        int row = (tid >> 6) + i * 4;
        tl[row][tid & 63] = sp[(size_t)row * TT + (tid & 63)];
    }
    __syncthreads();
    f16* dp = dst + ((size_t)b * TT + t0) * 512 + c0;
#pragma unroll
    for (int i = 0; i < 16; i++) {
        int t = (tid >> 6) + i * 4;
        dp[(size_t)t * 512 + (tid & 63)] = (f16)tl[tid & 63][t];
    }
}

// ---------------- QKV grouped conv as 5-tap MFMA GEMM ----------------
__global__ __launch_bounds__(256) void qkv_mfma(
    const f16* __restrict__ xT, const f16* __restrict__ WqP, const float* __restrict__ bq,
    f16* __restrict__ qk16, f16* __restrict__ vb16)
{
    __shared__ f16 xs[320 * 64];   // rows t0-32 .. t0+288, 64 ci
    int tid = threadIdx.x;
    int b = blockIdx.x >> 5;
    int t0 = (blockIdx.x & 31) * 256;
    int m = blockIdx.y;            // 0..23
    int ob = m * 64;
    int g = m / 3;

    const f16* xb = xT + ((size_t)b * TT) * 512 + g * 64;
#pragma unroll
    for (int lp = 0; lp < 10; lp++) {
        int q = tid + lp * 256;          // < 2560
        int row = q >> 3, c16 = q & 7;
        int t = t0 - 32 + row;
        half8 v = {};
        if ((unsigned)t < (unsigned)TT) v = *(const half8*)(xb + (size_t)t * 512 + c16 * 8);
        lds_write_chunk(xs, row, c16, v);
    }
    __syncthreads();

    int wid = tid >> 6, l = tid & 63;
    int ln31 = l & 31, lhi = l >> 5;
    floatx16 acc[2][2] = {};
#pragma unroll
    for (int kh = 0; kh < 5; kh++) {
#pragma unroll
        for (int ks = 0; ks < 4; ks++) {
            int fi = ((m * 2) * 5 + kh) * 4 + ks;
            half8 a0 = *(const half8*)(WqP + (size_t)fi * 512 + l * 8);
            half8 a1 = *(const half8*)(WqP + (size_t)(fi + 20) * 512 + l * 8);
            int chunk = ks * 2 + lhi;
            int r0 = wid * 64 + kh * 16 + ln31;
            half8 b0 = lds_read_frag(xs, r0, chunk);
            half8 b1 = lds_read_frag(xs, r0 + 32, chunk);
            acc[0][0] = MFMA(a0, b0, acc[0][0]);
            acc[0][1] = MFMA(a0, b1, acc[0][1]);
            acc[1][0] = MFMA(a1, b0, acc[1][0]);
            acc[1][1] = MFMA(a1, b1, acc[1][1]);
        }
    }
#pragma unroll
    for (int mf = 0; mf < 2; mf++)
#pragma unroll
        for (int nf = 0; nf < 2; nf++)
#pragma unroll
            for (int r = 0; r < 16; r++) {
                int o = ob + mf * 32 + (r & 3) + 8 * (r >> 2) + 4 * lhi;
                int t = t0 + wid * 64 + nf * 32 + ln31;
                float val = acc[mf][nf][r] + bq[o];
                if (o < 1024)
                    qk16[((size_t)b * 1024 + o) * TT + t] = (f16)val;
                else
                    vb16[((size_t)b * 512 + (o - 1024)) * TT + t] = (f16)val;
            }
}

// ---------------- softmax over d=8192 for q, per (b,w)  [f16 io, f32 math] ----------------
__global__ __launch_bounds__(256) void softmax_q(f16* __restrict__ qk16)
{
    int w = blockIdx.x, b = blockIdx.y, tid = threadIdx.x;
    f16* base = qk16 + (size_t)b * 1024 * TT + (size_t)w * 16;

    float val[32];
    float mx = -1e30f;
#pragma unroll
    for (int kk = 0; kk < 32; kk++) {
        int e = tid + kk * 256;
        float v = (float)base[((size_t)(e >> 4)) * TT + (e & 15)];
        val[kk] = v;
        mx = fmaxf(mx, v);
    }
#pragma unroll
    for (int o = 32; o > 0; o >>= 1) mx = fmaxf(mx, __shfl_xor(mx, o));
    __shared__ float red[4];
    int wv = tid >> 6;
    if ((tid & 63) == 0) red[wv] = mx;
    __syncthreads();
    mx = fmaxf(fmaxf(red[0], red[1]), fmaxf(red[2], red[3]));

    float s = 0.f;
#pragma unroll
    for (int kk = 0; kk < 32; kk++) { val[kk] = __expf(val[kk] - mx); s += val[kk]; }
#pragma unroll
    for (int o = 32; o > 0; o >>= 1) s += __shfl_xor(s, o);
    __syncthreads();
    if ((tid & 63) == 0) red[wv] = s;
    __syncthreads();
    s = red[0] + red[1] + red[2] + red[3];
    float inv = 1.f / s;
#pragma unroll
    for (int kk = 0; kk < 32; kk++) {
        int e = tid + kk * 256;
        base[((size_t)(e >> 4)) * TT + (e & 15)] = (f16)(val[kk] * inv);
    }
}

// ---------------- softmax over w=512 for k (+ drop mask), per (b,c) [f16 io] ----------------
__global__ __launch_bounds__(256) void softmax_k(
    f16* __restrict__ qk16, const float* __restrict__ mask)
{
    int c = blockIdx.x, b = blockIdx.y, tid = threadIdx.x;
    f16* kp = qk16 + ((size_t)(b * 1024 + 512 + c)) * TT;
    const float* mp = mask + ((size_t)(b * 512 + c)) * TT;

    float val[32];
    float mx = -1e30f;
#pragma unroll
    for (int kk = 0; kk < 32; kk++) {
        int e = tid + kk * 256;       // p = e&15 = tid&15 (const per thread)
        float v = (float)kp[e] + mp[e] * NEGC;
        val[kk] = v;
        mx = fmaxf(mx, v);
    }
    mx = fmaxf(mx, __shfl_xor(mx, 16));
    mx = fmaxf(mx, __shfl_xor(mx, 32));
    __shared__ float red[4][16];
    int wv = tid >> 6, ln = tid & 63;
    if (ln < 16) red[wv][ln] = mx;
    __syncthreads();
    int p = tid & 15;
    mx = fmaxf(fmaxf(red[0][p], red[1][p]), fmaxf(red[2][p], red[3][p]));

    float s = 0.f;
#pragma unroll
    for (int kk = 0; kk < 32; kk++) { val[kk] = __expf(val[kk] - mx); s += val[kk]; }
    s += __shfl_xor(s, 16);
    s += __shfl_xor(s, 32);
    __syncthreads();
    if (ln < 16) red[wv][ln] = s;
    __syncthreads();
    s = red[0][p] + red[1][p] + red[2][p] + red[3][p];
    float inv = 1.f / s;
#pragma unroll
    for (int kk = 0; kk < 32; kk++)
        kp[tid + kk * 256] = (f16)(val[kk] * inv);
}

// ---------------- v permute: vb16[b][c][t] -> vpw[b][c][p][w]  (t = w*16+p) ----------------
__global__ __launch_bounds__(256) void vperm(
    const f16* __restrict__ vb16, f16* __restrict__ vpw)
{
    int c = blockIdx.x, b = blockIdx.y, tid = threadIdx.x;
    __shared__ f16 tl[512 * 17];
    const f16* ip = vb16 + ((size_t)b * 512 + c) * TT;
    f16* op = vpw + ((size_t)b * 512 + c) * 16 * 512;
#pragma unroll
    for (int i = 0; i < 32; i++) {
        int e = tid + i * 256;
        tl[(e >> 4) * 17 + (e & 15)] = ip[e];
    }
    __syncthreads();
#pragma unroll
    for (int i = 0; i < 32; i++) {
        int o = tid + i * 256;           // o = p*512 + w
        op[o] = tl[(o & 511) * 17 + (o >> 9)];
    }
}

// ---------------- S partials: Sp[kz][b][iw][w] = sum_{d-slice} q.k, d = c*16+p ----------------
// Reads q,k in native [o][t] layout; K-slice kz covers c in [kz*32, kz*32+32).
__global__ __launch_bounds__(256) void qk_mfma(
    const f16* __restrict__ qk16, float* __restrict__ Spart)
{
    __shared__ f16 As[128 * 64];
    __shared__ f16 Bs[128 * 64];
    int tid = threadIdx.x;
    int mt = blockIdx.x & 3, nt = blockIdx.x >> 2;
    int kz = blockIdx.y, b = blockIdx.z;
    int iw0 = mt * 128, w0 = nt * 128;
    const f16* qb_ = qk16 + (size_t)b * 1024 * TT;
    const f16* kb_ = qb_ + (size_t)512 * TT;
    int wid = tid >> 6, l = tid & 63, ln31 = l & 31, lhi = l >> 5;
    int wm = (wid >> 1) * 64, wn = (wid & 1) * 64;
    floatx16 acc[2][2] = {};

    for (int step = 0; step < 8; step++) {
        int c_abs = kz * 32 + step * 4 + wid;    // wave wid stages channel c_abs
        __syncthreads();
        const f16* qrow = qb_ + (size_t)c_abs * TT + iw0 * 16;
        const f16* krow = kb_ + (size_t)c_abs * TT + w0 * 16;
#pragma unroll
        for (int i = 0; i < 4; i++) {
            int j = l + i * 64;                  // 0..255 chunk within 2048-elem row-slab
            int row = j >> 1, ch = wid * 2 + (j & 1);
            lds_write_chunk(As, row, ch, *(const half8*)(qrow + j * 8));
            lds_write_chunk(Bs, row, ch, *(const half8*)(krow + j * 8));
        }
        __syncthreads();
#pragma unroll
        for (int ks = 0; ks < 4; ks++) {
            int chunk = ks * 2 + lhi;
            half8 a0 = lds_read_frag(As, wm + ln31, chunk);
            half8 a1 = lds_read_frag(As, wm + 32 + ln31, chunk);
            half8 b0 = lds_read_frag(Bs, wn + ln31, chunk);
            half8 b1 = lds_read_frag(Bs, wn + 32 + ln31, chunk);
            acc[0][0] = MFMA(a0, b0, acc[0][0]);
            acc[0][1] = MFMA(a0, b1, acc[0][1]);
            acc[1][0] = MFMA(a1, b0, acc[1][0]);
            acc[1][1] = MFMA(a1, b1, acc[1][1]);
        }
    }
    float* Sp = Spart + ((size_t)(kz * 2 + b) * 512) * 512;
#pragma unroll
    for (int mf = 0; mf < 2; mf++)
#pragma unroll
        for (int nf = 0; nf < 2; nf++)
#pragma unroll
            for (int r = 0; r < 16; r++) {
                int iw = iw0 + wm + mf * 32 + (r & 3) + 8 * (r >> 2) + 4 * lhi;
                int w = w0 + wn + nf * 32 + ln31;
                Sp[(size_t)iw * 512 + w] = acc[mf][nf][r];
            }
}

// ---------------- reduce 16 partials -> f16 S ----------------
__global__ __launch_bounds__(256) void s_reduce(
    const float* __restrict__ Spart, f16* __restrict__ S16)
{
    int id = blockIdx.x * 256 + threadIdx.x;     // < 524288
    float s = 0.f;
#pragma unroll
    for (int kz = 0; kz < 16; kz++) s += Spart[(size_t)kz * 524288 + id];
    S16[id] = (f16)s;
}

// ---------------- abuf_T[b][iw*16+p][c] = sum_w S[b][iw][w] * vpw[b][c][p][w] ----------------
__global__ __launch_bounds__(256) void sv_mfma(
    const f16* __restrict__ S16, const f16* __restrict__ vpw, f16* __restrict__ abufT)
{
    __shared__ f16 As[128 * 64];
    __shared__ f16 Bs[128 * 64];
    int tid = threadIdx.x;
    int mt = blockIdx.x, nt = blockIdx.y;
    int b = blockIdx.z >> 4, p = blockIdx.z & 15;
    int iw0 = mt * 128, c0n = nt * 128;
    const f16* Sb = S16 + (size_t)b * 512 * 512;
    const f16* vb_ = vpw + ((size_t)b * 512) * 16 * 512;
    int wid = tid >> 6, l = tid & 63, ln31 = l & 31, lhi = l >> 5;
    int wm = (wid >> 1) * 64, wn = (wid & 1) * 64;
    floatx16 acc[2][2] = {};

    for (int step = 0; step < 8; step++) {
        int w0k = step * 64;
        __syncthreads();
#pragma unroll
        for (int li = 0; li < 4; li++) {
            int q = tid + li * 256;
            int row = q >> 3, c16 = q & 7;
            half8 av = *(const half8*)(Sb + (size_t)(iw0 + row) * 512 + w0k + c16 * 8);
            half8 bv = *(const half8*)(vb_ + ((size_t)(c0n + row) * 16 + p) * 512 + w0k + c16 * 8);
            lds_write_chunk(As, row, c16, av);
            lds_write_chunk(Bs, row, c16, bv);
        }
        __syncthreads();
#pragma unroll
        for (int ks = 0; ks < 4; ks++) {
            int chunk = ks * 2 + lhi;
            half8 a0 = lds_read_frag(As, wm + ln31, chunk);
            half8 a1 = lds_read_frag(As, wm + 32 + ln31, chunk);
            half8 b0 = lds_read_frag(Bs, wn + ln31, chunk);
            half8 b1 = lds_read_frag(Bs, wn + 32 + ln31, chunk);
            acc[0][0] = MFMA(a0, b0, acc[0][0]);
            acc[0][1] = MFMA(a0, b1, acc[0][1]);
            acc[1][0] = MFMA(a1, b0, acc[1][0]);
            acc[1][1] = MFMA(a1, b1, acc[1][1]);
        }
    }
#pragma unroll
    for (int mf = 0; mf < 2; mf++)
#pragma unroll
        for (int nf = 0; nf < 2; nf++)
#pragma unroll
            for (int r = 0; r < 16; r++) {
                int iw = iw0 + wm + mf * 32 + (r & 3) + 8 * (r >> 2) + 4 * lhi;
                int c = c0n + wn + nf * 32 + ln31;
                int t = iw * 16 + p;
                abufT[((size_t)b * TT + t) * 512 + c] = (f16)acc[mf][nf][r];
            }
}

// ---------------- out conv1d as 3-tap MFMA GEMM (packed weights) ----------------
__global__ __launch_bounds__(256) void out_mfma(
    const f16* __restrict__ abufT, const f16* __restrict__ WoP, const float* __restrict__ bo,
    float* __restrict__ out)
{
    __shared__ f16 Bs[130 * 64];
    int tid = threadIdx.x;
    int b = blockIdx.x >> 6;
    int t0 = (blockIdx.x & 63) * 128;
    int co0 = blockIdx.y * 128;
    const f16* ab = abufT + ((size_t)b * TT) * 512;
    int wid = tid >> 6, l = tid & 63, ln31 = l & 31, lhi = l >> 5;
    int wm = (wid >> 1) * 64, wn = (wid & 1) * 64;
    int cb0 = blockIdx.y * 4 + (wid >> 1) * 2;
    floatx16 acc[2][2] = {};

    for (int kc = 0; kc < 8; kc++) {
        int ci0 = kc * 64;
        __syncthreads();
#pragma unroll
        for (int li = 0; li < 5; li++) {
            int q = tid + li * 256;
            if (q < 1040) {
                int row = q >> 3, c16 = q & 7;
                int t = t0 - 1 + row;
                half8 v = {};
                if ((unsigned)t < (unsigned)TT) v = *(const half8*)(ab + (size_t)t * 512 + ci0 + c16 * 8);
                lds_write_chunk(Bs, row, c16, v);
            }
        }
        __syncthreads();
#pragma unroll
        for (int kt = 0; kt < 3; kt++) {
#pragma unroll
            for (int ks = 0; ks < 4; ks++) {
                int fi = ((cb0 * 3 + kt) * 8 + kc) * 4 + ks;
                half8 a0 = *(const half8*)(WoP + (size_t)fi * 512 + l * 8);
                half8 a1 = *(const half8*)(WoP + (size_t)(fi + 96) * 512 + l * 8);
                int chunk = ks * 2 + lhi;
                int r0 = wn + ln31 + kt;
                half8 b0 = lds_read_frag(Bs, r0, chunk);
                half8 b1 = lds_read_frag(Bs, r0 + 32, chunk);
                acc[0][0] = MFMA(a0, b0, acc[0][0]);
                acc[0][1] = MFMA(a0, b1, acc[0][1]);
                acc[1][0] = MFMA(a1, b0, acc[1][0]);
                acc[1][1] = MFMA(a1, b1, acc[1][1]);
            }
        }
    }
#pragma unroll
    for (int mf = 0; mf < 2; mf++)
#pragma unroll
        for (int nf = 0; nf < 2; nf++)
#pragma unroll
            for (int r = 0; r < 16; r++) {
                int co = co0 + wm + mf * 32 + (r & 3) + 8 * (r >> 2) + 4 * lhi;
                int t = t0 + wn + nf * 32 + ln31;
                out[((size_t)b * 512 + co) * TT + t] = acc[mf][nf][r] + bo[co];
            }
}

extern "C" void kernel_launch(void* const* d_in, const int* in_sizes, int n_in,
                              void* d_out, int out_size, void* d_ws, size_t ws_size,
                              hipStream_t stream)
{
    const float* x    = (const float*)d_in[0];   // (2,512,8192)
    const float* Wq   = (const float*)d_in[1];   // (1536,64,5,1)
    const float* bq   = (const float*)d_in[2];   // (1536,)
    const float* Wo   = (const float*)d_in[3];   // (512,512,3)
    const float* bo   = (const float*)d_in[4];   // (512,)
    const float* mask = (const float*)d_in[5];   // (2,512,512,16)
    float* out = (float*)d_out;                  // (2,512,8192)
    (void)in_sizes; (void)n_in; (void)out_size; (void)ws_size;

    char* W = (char*)d_ws;
    f16*   qk16  = (f16*)W;                        // 32 MiB: [b][o<512:q, 512..1024:k][t]
    f16*   xT    = (f16*)(W + 33554432);           // 16 MiB (aliased as abufT after qkv consumed)
    f16*   abufT = xT;
    f16*   vb16  = (f16*)(W + 50331648);           // 16 MiB
    f16*   vpw   = (f16*)(W + 67108864);           // 16 MiB
    float* Spart = (float*)(W + 83886080);         // 32 MiB: [16][2][512][512] f32
    f16*   S16   = (f16*)(W + 117440512);          // 1 MiB
    f16*   WqP   = (f16*)(W + 118489088);          // 960 KiB
    f16*   WoP   = (f16*)(W + 119472128);          // 1.5 MiB

    prep_w<<<4992, 256, 0, stream>>>(Wq, Wo, WqP, WoP);
    transpose_cvt<<<dim3(128, 8, 2), 256, 0, stream>>>(x, (size_t)512 * TT, xT);
    qkv_mfma<<<dim3(64, 24), 256, 0, stream>>>(xT, WqP, bq, qk16, vb16);
    softmax_q<<<dim3(512, 2), 256, 0, stream>>>(qk16);
    softmax_k<<<dim3(512, 2), 256, 0, stream>>>(qk16, mask);
    vperm<<<dim3(512, 2), 256, 0, stream>>>(vb16, vpw);
    qk_mfma<<<dim3(16, 16, 2), 256, 0, stream>>>(qk16, Spart);
    s_reduce<<<2048, 256, 0, stream>>>(Spart, S16);
    sv_mfma<<<dim3(4, 4, 32), 256, 0, stream>>>(S16, vpw, abufT);
    out_mfma<<<dim3(128, 4), 256, 0, stream>>>(abufT, WoP, bo, out);
}

// Round 8
// 283.103 us; speedup vs baseline: 7.1871x; 1.0133x over previous
//
#include <hip/hip_runtime.h>

#define TT 8192
#define NEGC -1000000000.0f

typedef _Float16 f16;
typedef f16 half8 __attribute__((ext_vector_type(8)));
typedef float floatx16 __attribute__((ext_vector_type(16)));

#define MFMA(a, b, c) __builtin_amdgcn_mfma_f32_32x32x16_f16(a, b, c, 0, 0, 0)

// LDS operand tiles: [row][64 k] f16, row stride 128B, 16B chunks XOR-swizzled by (row&7).
__device__ __forceinline__ half8 lds_read_frag(const f16* lds, int row, int chunk) {
    return *(const half8*)(lds + row * 64 + ((chunk ^ (row & 7)) << 3));
}
__device__ __forceinline__ void lds_write_chunk(f16* lds, int row, int chunk, half8 v) {
    *(half8*)(lds + row * 64 + ((chunk ^ (row & 7)) << 3)) = v;
}

// ---------------- prep: weights -> fragment-major packed fp16 ----------------
__global__ __launch_bounds__(256) void prep_w(
    const float* __restrict__ Wq, const float* __restrict__ Wo,
    f16* __restrict__ WqP, f16* __restrict__ WoP)
{
    int i = blockIdx.x * 256 + threadIdx.x;
    const int NQ = 48 * 5 * 4 * 512;        // 491520
    if (i < NQ) {
        int idx = i & 511, l = idx >> 3, e = idx & 7;
        int fi = i >> 9;
        int ks = fi & 3; fi >>= 2;
        int kh = fi % 5; int cb = fi / 5;
        int o = cb * 32 + (l & 31);
        int ci = ks * 16 + (l >> 5) * 8 + e;
        WqP[i] = (f16)Wq[o * 320 + ci * 5 + kh];
    } else {
        int j = i - NQ;
        if (j < 16 * 3 * 8 * 4 * 512) {     // 786432
            int idx = j & 511, l = idx >> 3, e = idx & 7;
            int fj = j >> 9;
            int ks = fj & 3; fj >>= 2;
            int kc = fj & 7; fj >>= 3;
            int kt = fj % 3; int cb = fj / 3;
            int co = cb * 32 + (l & 31);
            int ci = kc * 64 + ks * 16 + (l >> 5) * 8 + e;
            WoP[j] = (f16)Wo[co * 1536 + ci * 3 + kt];
        }
    }
}

// ---------------- transpose+cvt: src[b][512 c][8192 t] f32 -> dst[b][8192 t][512 c] f16 ----------------
__global__ __launch_bounds__(256) void transpose_cvt(
    const float* __restrict__ src, size_t bstride, f16* __restrict__ dst)
{
    __shared__ float tl[64][65];
    int tid = threadIdx.x;
    int t0 = blockIdx.x * 64, c0 = blockIdx.y * 64, b = blockIdx.z;
    const float* sp = src + (size_t)b * bstride + (size_t)c0 * TT + t0;
#pragma unroll
    for (int i = 0; i < 16; i++) {
        int row = (tid >> 6) + i * 4;
        tl[row][tid & 63] = sp[(size_t)row * TT + (tid & 63)];
    }
    __syncthreads();
    f16* dp = dst + ((size_t)b * TT + t0) * 512 + c0;
#pragma unroll
    for (int i = 0; i < 16; i++) {
        int t = (tid >> 6) + i * 4;
        dp[(size_t)t * 512 + (tid & 63)] = (f16)tl[tid & 63][t];
    }
}

// ---------------- QKV grouped conv, fused q/k/v per group: block = (g, 128 t) ----------------
__global__ __launch_bounds__(256) void qkv_mfma(
    const f16* __restrict__ xT, const f16* __restrict__ WqP, const float* __restrict__ bq,
    f16* __restrict__ qk16, f16* __restrict__ vb16)
{
    __shared__ f16 xs[192 * 64];   // rows t0-32 .. t0+159, 64 ci
    int tid = threadIdx.x;
    int b = blockIdx.x >> 6;
    int t0 = (blockIdx.x & 63) * 128;
    int g = blockIdx.y;            // 0..7

    const f16* xb = xT + ((size_t)b * TT) * 512 + g * 64;
#pragma unroll
    for (int lp = 0; lp < 6; lp++) {
        int q = tid + lp * 256;          // < 1536
        int row = q >> 3, c16 = q & 7;
        int t = t0 - 32 + row;
        half8 v = {};
        if ((unsigned)t < (unsigned)TT) v = *(const half8*)(xb + (size_t)t * 512 + c16 * 8);
        lds_write_chunk(xs, row, c16, v);
    }
    __syncthreads();

    int wid = tid >> 6, l = tid & 63;
    int ln31 = l & 31, lhi = l >> 5;
    floatx16 acc[6] = {};
#pragma unroll
    for (int kh = 0; kh < 5; kh++) {
#pragma unroll
        for (int ks = 0; ks < 4; ks++) {
            int chunk = ks * 2 + lhi;
            half8 bfrag = lds_read_frag(xs, wid * 32 + kh * 16 + ln31, chunk);
#pragma unroll
            for (int cf = 0; cf < 6; cf++) {
                int fi = ((g * 6 + cf) * 5 + kh) * 4 + ks;
                half8 a = *(const half8*)(WqP + (size_t)fi * 512 + l * 8);
                acc[cf] = MFMA(a, bfrag, acc[cf]);
            }
        }
    }
    int t = t0 + wid * 32 + ln31;
#pragma unroll
    for (int cf = 0; cf < 6; cf++)
#pragma unroll
        for (int r = 0; r < 16; r++) {
            int o = g * 192 + cf * 32 + (r & 3) + 8 * (r >> 2) + 4 * lhi;
            float val = acc[cf][r] + bq[o];
            if (o < 1024)
                qk16[((size_t)b * 1024 + o) * TT + t] = (f16)val;
            else
                vb16[((size_t)b * 512 + (o - 1024)) * TT + t] = (f16)val;
        }
}

// ---------------- softmax over d=8192 for q: coalesced, per-WORD (m,S) ----------------
// block = 1024 thr covering 64 t-cols (= 4 whole words) x 16 c-strips of 32.
// Reduction: per-(strip,lt) online -> per-lt (over strips) -> per-word (over 16 lt).
__global__ __launch_bounds__(1024) void softmax_q(f16* __restrict__ qk16)
{
    __shared__ float redm[16][64], reds[16][64];
    __shared__ float colM[64], colS[64];
    int tid = threadIdx.x;
    int lt = tid & 63, strip = tid >> 6;
    int b = blockIdx.y;
    f16* base = qk16 + (size_t)b * 1024 * TT + blockIdx.x * 64 + lt;

    float m = -1e30f, s = 0.f;
#pragma unroll 4
    for (int cc = 0; cc < 32; cc++) {
        int c = strip * 32 + cc;
        float v = (float)base[(size_t)c * TT];
        float nm = fmaxf(m, v);
        s = s * __expf(m - nm) + __expf(v - nm);
        m = nm;
    }
    redm[strip][lt] = m; reds[strip][lt] = s;
    __syncthreads();
    if (strip == 0) {
        float M = -1e30f, S = 0.f;
#pragma unroll
        for (int k = 0; k < 16; k++) {
            float mm = redm[k][lt], ss = reds[k][lt];
            float nm = fmaxf(M, mm);
            S = S * __expf(M - nm) + ss * __expf(mm - nm);
            M = nm;
        }
        colM[lt] = M; colS[lt] = S;
    }
    __syncthreads();
    // combine the 16 t-columns of this thread's word
    float M = -1e30f, S = 0.f;
    int w0 = lt & 48;
#pragma unroll
    for (int j = 0; j < 16; j++) {
        float mm = colM[w0 + j], ss = colS[w0 + j];
        float nm = fmaxf(M, mm);
        S = S * __expf(M - nm) + ss * __expf(mm - nm);
        M = nm;
    }
    float inv = 1.f / S;
#pragma unroll 4
    for (int cc = 0; cc < 32; cc++) {
        int c = strip * 32 + cc;
        float v = (float)base[(size_t)c * TT];
        base[(size_t)c * TT] = (f16)(__expf(v - M) * inv);
    }
}

// ---------------- softmax over w=512 for k (+ drop mask), per (b,c) [f16 io] ----------------
__global__ __launch_bounds__(256) void softmax_k(
    f16* __restrict__ qk16, const float* __restrict__ mask)
{
    int c = blockIdx.x, b = blockIdx.y, tid = threadIdx.x;
    f16* kp = qk16 + ((size_t)(b * 1024 + 512 + c)) * TT;
    const float* mp = mask + ((size_t)(b * 512 + c)) * TT;

    float val[32];
    float mx = -1e30f;
#pragma unroll
    for (int kk = 0; kk < 32; kk++) {
        int e = tid + kk * 256;       // p = e&15 = tid&15 (const per thread)
        float v = (float)kp[e] + mp[e] * NEGC;
        val[kk] = v;
        mx = fmaxf(mx, v);
    }
    mx = fmaxf(mx, __shfl_xor(mx, 16));
    mx = fmaxf(mx, __shfl_xor(mx, 32));
    __shared__ float red[4][16];
    int wv = tid >> 6, ln = tid & 63;
    if (ln < 16) red[wv][ln] = mx;
    __syncthreads();
    int p = tid & 15;
    mx = fmaxf(fmaxf(red[0][p], red[1][p]), fmaxf(red[2][p], red[3][p]));

    float s = 0.f;
#pragma unroll
    for (int kk = 0; kk < 32; kk++) { val[kk] = __expf(val[kk] - mx); s += val[kk]; }
    s += __shfl_xor(s, 16);
    s += __shfl_xor(s, 32);
    __syncthreads();
    if (ln < 16) red[wv][ln] = s;
    __syncthreads();
    s = red[0][p] + red[1][p] + red[2][p] + red[3][p];
    float inv = 1.f / s;
#pragma unroll
    for (int kk = 0; kk < 32; kk++)
        kp[tid + kk * 256] = (f16)(val[kk] * inv);
}

// ---------------- v permute: vb16[b][c][t] -> vpw[b][c][p][w]  (t = w*16+p) ----------------
__global__ __launch_bounds__(256) void vperm(
    const f16* __restrict__ vb16, f16* __restrict__ vpw)
{
    int c = blockIdx.x, b = blockIdx.y, tid = threadIdx.x;
    __shared__ f16 tl[512 * 17];
    const f16* ip = vb16 + ((size_t)b * 512 + c) * TT;
    f16* op = vpw + ((size_t)b * 512 + c) * 16 * 512;
#pragma unroll
    for (int i = 0; i < 32; i++) {
        int e = tid + i * 256;
        tl[(e >> 4) * 17 + (e & 15)] = ip[e];
    }
    __syncthreads();
#pragma unroll
    for (int i = 0; i < 32; i++) {
        int o = tid + i * 256;           // o = p*512 + w
        op[o] = tl[(o & 511) * 17 + (o >> 9)];
    }
}

// ---------------- S partials: Sp16[kz][b][iw][w] = sum_{d-slice} q.k, d = c*16+p ----------------
__global__ __launch_bounds__(256) void qk_mfma(
    const f16* __restrict__ qk16, f16* __restrict__ Sp16)
{
    __shared__ f16 As[128 * 64];
    __shared__ f16 Bs[128 * 64];
    int tid = threadIdx.x;
    int mt = blockIdx.x & 3, nt = blockIdx.x >> 2;
    int kz = blockIdx.y, b = blockIdx.z;
    int iw0 = mt * 128, w0 = nt * 128;
    const f16* qb_ = qk16 + (size_t)b * 1024 * TT;
    const f16* kb_ = qb_ + (size_t)512 * TT;
    int wid = tid >> 6, l = tid & 63, ln31 = l & 31, lhi = l >> 5;
    int wm = (wid >> 1) * 64, wn = (wid & 1) * 64;
    floatx16 acc[2][2] = {};

    for (int step = 0; step < 8; step++) {
        int c_abs = kz * 32 + step * 4 + wid;    // wave wid stages channel c_abs
        __syncthreads();
        const f16* qrow = qb_ + (size_t)c_abs * TT + iw0 * 16;
        const f16* krow = kb_ + (size_t)c_abs * TT + w0 * 16;
#pragma unroll
        for (int i = 0; i < 4; i++) {
            int j = l + i * 64;                  // 0..255 chunk within 2048-elem row-slab
            int row = j >> 1, ch = wid * 2 + (j & 1);
            lds_write_chunk(As, row, ch, *(const half8*)(qrow + j * 8));
            lds_write_chunk(Bs, row, ch, *(const half8*)(krow + j * 8));
        }
        __syncthreads();
#pragma unroll
        for (int ks = 0; ks < 4; ks++) {
            int chunk = ks * 2 + lhi;
            half8 a0 = lds_read_frag(As, wm + ln31, chunk);
            half8 a1 = lds_read_frag(As, wm + 32 + ln31, chunk);
            half8 b0 = lds_read_frag(Bs, wn + ln31, chunk);
            half8 b1 = lds_read_frag(Bs, wn + 32 + ln31, chunk);
            acc[0][0] = MFMA(a0, b0, acc[0][0]);
            acc[0][1] = MFMA(a0, b1, acc[0][1]);
            acc[1][0] = MFMA(a1, b0, acc[1][0]);
            acc[1][1] = MFMA(a1, b1, acc[1][1]);
        }
    }
    f16* Sp = Sp16 + ((size_t)(kz * 2 + b)) * 262144;
#pragma unroll
    for (int mf = 0; mf < 2; mf++)
#pragma unroll
        for (int nf = 0; nf < 2; nf++)
#pragma unroll
            for (int r = 0; r < 16; r++) {
                int iw = iw0 + wm + mf * 32 + (r & 3) + 8 * (r >> 2) + 4 * lhi;
                int w = w0 + wn + nf * 32 + ln31;
                Sp[(size_t)iw * 512 + w] = (f16)acc[mf][nf][r];
            }
}

// ---------------- reduce 16 f16 partials -> f16 S ----------------
__global__ __launch_bounds__(256) void s_reduce(
    const f16* __restrict__ Sp16, f16* __restrict__ S16)
{
    int id = blockIdx.x * 256 + threadIdx.x;     // < 65536, 8 elems each
    float acc[8] = {};
#pragma unroll
    for (int kz = 0; kz < 16; kz++) {
        half8 v = *(const half8*)(Sp16 + (size_t)kz * 524288 + (size_t)id * 8);
#pragma unroll
        for (int j = 0; j < 8; j++) acc[j] += (float)v[j];
    }
    half8 o;
#pragma unroll
    for (int j = 0; j < 8; j++) o[j] = (f16)acc[j];
    *(half8*)(S16 + (size_t)id * 8) = o;
}

// ---------------- abuf_T[b][iw*16+p][c] = sum_w S[b][iw][w] * vpw[b][c][p][w] ----------------
__global__ __launch_bounds__(256) void sv_mfma(
    const f16* __restrict__ S16, const f16* __restrict__ vpw, f16* __restrict__ abufT)
{
    __shared__ f16 As[128 * 64];
    __shared__ f16 Bs[128 * 64];
    int tid = threadIdx.x;
    int mt = blockIdx.x, nt = blockIdx.y;
    int b = blockIdx.z >> 4, p = blockIdx.z & 15;
    int iw0 = mt * 128, c0n = nt * 128;
    const f16* Sb = S16 + (size_t)b * 512 * 512;
    const f16* vb_ = vpw + ((size_t)b * 512) * 16 * 512;
    int wid = tid >> 6, l = tid & 63, ln31 = l & 31, lhi = l >> 5;
    int wm = (wid >> 1) * 64, wn = (wid & 1) * 64;
    floatx16 acc[2][2] = {};

    for (int step = 0; step < 8; step++) {
        int w0k = step * 64;
        __syncthreads();
#pragma unroll
        for (int li = 0; li < 4; li++) {
            int q = tid + li * 256;
            int row = q >> 3, c16 = q & 7;
            half8 av = *(const half8*)(Sb + (size_t)(iw0 + row) * 512 + w0k + c16 * 8);
            half8 bv = *(const half8*)(vb_ + ((size_t)(c0n + row) * 16 + p) * 512 + w0k + c16 * 8);
            lds_write_chunk(As, row, c16, av);
            lds_write_chunk(Bs, row, c16, bv);
        }
        __syncthreads();
#pragma unroll
        for (int ks = 0; ks < 4; ks++) {
            int chunk = ks * 2 + lhi;
            half8 a0 = lds_read_frag(As, wm + ln31, chunk);
            half8 a1 = lds_read_frag(As, wm + 32 + ln31, chunk);
            half8 b0 = lds_read_frag(Bs, wn + ln31, chunk);
            half8 b1 = lds_read_frag(Bs, wn + 32 + ln31, chunk);
            acc[0][0] = MFMA(a0, b0, acc[0][0]);
            acc[0][1] = MFMA(a0, b1, acc[0][1]);
            acc[1][0] = MFMA(a1, b0, acc[1][0]);
            acc[1][1] = MFMA(a1, b1, acc[1][1]);
        }
    }
#pragma unroll
    for (int mf = 0; mf < 2; mf++)
#pragma unroll
        for (int nf = 0; nf < 2; nf++)
#pragma unroll
            for (int r = 0; r < 16; r++) {
                int iw = iw0 + wm + mf * 32 + (r & 3) + 8 * (r >> 2) + 4 * lhi;
                int c = c0n + wn + nf * 32 + ln31;
                int t = iw * 16 + p;
                abufT[((size_t)b * TT + t) * 512 + c] = (f16)acc[mf][nf][r];
            }
}

// ---------------- out conv1d as 3-tap MFMA GEMM: wave tile 128co x 32t, acc[4] ----------------
__global__ __launch_bounds__(256) void out_mfma(
    const f16* __restrict__ abufT, const f16* __restrict__ WoP, const float* __restrict__ bo,
    float* __restrict__ out)
{
    __shared__ f16 Bs[130 * 64];
    int tid = threadIdx.x;
    int b = blockIdx.x >> 6;
    int t0 = (blockIdx.x & 63) * 128;
    int cbb = blockIdx.y;                // co block of 128
    const f16* ab = abufT + ((size_t)b * TT) * 512;
    int wid = tid >> 6, l = tid & 63, ln31 = l & 31, lhi = l >> 5;
    floatx16 acc[4] = {};

    for (int kc = 0; kc < 8; kc++) {
        int ci0 = kc * 64;
        __syncthreads();
#pragma unroll
        for (int li = 0; li < 5; li++) {
            int q = tid + li * 256;
            if (q < 1040) {
                int row = q >> 3, c16 = q & 7;
                int t = t0 - 1 + row;
                half8 v = {};
                if ((unsigned)t < (unsigned)TT) v = *(const half8*)(ab + (size_t)t * 512 + ci0 + c16 * 8);
                lds_write_chunk(Bs, row, c16, v);
            }
        }
        __syncthreads();
#pragma unroll
        for (int kt = 0; kt < 3; kt++) {
#pragma unroll
            for (int ks = 0; ks < 4; ks++) {
                int chunk = ks * 2 + lhi;
                half8 bfrag = lds_read_frag(Bs, wid * 32 + ln31 + kt, chunk);
#pragma unroll
                for (int cf = 0; cf < 4; cf++) {
                    int fi = (((cbb * 4 + cf) * 3 + kt) * 8 + kc) * 4 + ks;
                    half8 a = *(const half8*)(WoP + (size_t)fi * 512 + l * 8);
                    acc[cf] = MFMA(a, bfrag, acc[cf]);
                }
            }
        }
    }
    int t = t0 + wid * 32 + ln31;
#pragma unroll
    for (int cf = 0; cf < 4; cf++)
#pragma unroll
        for (int r = 0; r < 16; r++) {
            int co = cbb * 128 + cf * 32 + (r & 3) + 8 * (r >> 2) + 4 * lhi;
            out[((size_t)b * 512 + co) * TT + t] = acc[cf][r] + bo[co];
        }
}

extern "C" void kernel_launch(void* const* d_in, const int* in_sizes, int n_in,
                              void* d_out, int out_size, void* d_ws, size_t ws_size,
                              hipStream_t stream)
{
    const float* x    = (const float*)d_in[0];   // (2,512,8192)
    const float* Wq   = (const float*)d_in[1];   // (1536,64,5,1)
    const float* bq   = (const float*)d_in[2];   // (1536,)
    const float* Wo   = (const float*)d_in[3];   // (512,512,3)
    const float* bo   = (const float*)d_in[4];   // (512,)
    const float* mask = (const float*)d_in[5];   // (2,512,512,16)
    float* out = (float*)d_out;                  // (2,512,8192)
    (void)in_sizes; (void)n_in; (void)out_size; (void)ws_size;

    char* W = (char*)d_ws;
    f16*   qk16  = (f16*)W;                        // 32 MiB: [b][o<512:q, 512..1024:k][t]
    f16*   xT    = (f16*)(W + 33554432);           // 16 MiB (aliased as abufT after qkv consumed)
    f16*   abufT = xT;
    f16*   vb16  = (f16*)(W + 50331648);           // 16 MiB
    f16*   vpw   = (f16*)(W + 67108864);           // 16 MiB
    f16*   Sp16  = (f16*)(W + 83886080);           // 16 MiB: [16][2][512][512] f16
    f16*   S16   = (f16*)(W + 117440512);          // 1 MiB
    f16*   WqP   = (f16*)(W + 118489088);          // 960 KiB
    f16*   WoP   = (f16*)(W + 119472128);          // 1.5 MiB

    prep_w<<<4992, 256, 0, stream>>>(Wq, Wo, WqP, WoP);
    transpose_cvt<<<dim3(128, 8, 2), 256, 0, stream>>>(x, (size_t)512 * TT, xT);
    qkv_mfma<<<dim3(128, 8), 256, 0, stream>>>(xT, WqP, bq, qk16, vb16);
    softmax_q<<<dim3(128, 2), 1024, 0, stream>>>(qk16);
    softmax_k<<<dim3(512, 2), 256, 0, stream>>>(qk16, mask);
    vperm<<<dim3(512, 2), 256, 0, stream>>>(vb16, vpw);
    qk_mfma<<<dim3(16, 16, 2), 256, 0, stream>>>(qk16, Sp16);
    s_reduce<<<256, 256, 0, stream>>>(Sp16, S16);
    sv_mfma<<<dim3(4, 4, 32), 256, 0, stream>>>(S16, vpw, abufT);
    out_mfma<<<dim3(128, 4), 256, 0, stream>>>(abufT, WoP, bo, out);
}